// Round 1
// baseline (896.649 us; speedup 1.0000x reference)
//
#include <hip/hip_runtime.h>

// Residual VQ (L=4, K=4096, C=256, N=4096) — fp32 vector-ALU path.
// ws layout (floats):
//   enT [L][C][K]  = 4*256*4096 = 4194304   (normalized, transposed codebook)
//   r   [N][C]     = 1048576                (residual, updated per level)
//   inv [L][K]     = 16384
//   pval[N][4]     = 16384                  (per-K-slice argmax value)
//   pidx[N][4]     = 16384 (int)
//   ssq [L][N]     = 16384                  (per-vector residual sumsq per level)
// total ~20.3 MB

#define OFF_ENT 0
#define OFF_R   4194304
#define OFF_INV (OFF_R + 1048576)
#define OFF_PV  (OFF_INV + 16384)
#define OFF_PI  (OFF_PV + 16384)
#define OFF_SSQ (OFF_PI + 16384)

#define BETA 0.25f
#define EPSN 1e-12f

// ---- transpose z (B,C,H,W) -> r (N=B*HW, C) via 32x32 LDS tiles ----
__global__ __launch_bounds__(256) void k_prep_r(const float* __restrict__ z,
                                                float* __restrict__ r) {
  __shared__ float t[32][33];
  int id = blockIdx.x;                 // B * (C/32) * (HW/32) = 4*8*32 = 1024
  int b = id >> 8; int rem = id & 255; int ct = rem >> 5; int ht = rem & 31;
  int c0 = ct * 32, h0 = ht * 32;
  int col = threadIdx.x & 31, row0 = threadIdx.x >> 5;
#pragma unroll
  for (int p = 0; p < 4; ++p) {
    int row = row0 + p * 8;            // c offset
    t[row][col] = z[((b * 256 + c0 + row) << 10) + h0 + col];
  }
  __syncthreads();
#pragma unroll
  for (int p = 0; p < 4; ++p) {
    int row = row0 + p * 8;            // hw offset
    r[(b * 1024 + h0 + row) * 256 + c0 + col] = t[col][row];
  }
}

// ---- per-row inverse norms of codebook: one wave per row ----
__global__ __launch_bounds__(256) void k_prep_inv(const float* __restrict__ cb,
                                                  float* __restrict__ inv) {
  int w = threadIdx.x >> 6, lane = threadIdx.x & 63;
  int row = blockIdx.x * 4 + w;        // 0..16383
  float4 v = *(const float4*)(cb + row * 256 + lane * 4);
  float s = v.x * v.x + v.y * v.y + v.z * v.z + v.w * v.w;
#pragma unroll
  for (int off = 32; off; off >>= 1) s += __shfl_xor(s, off);
  if (lane == 0) inv[row] = 1.0f / fmaxf(sqrtf(s), EPSN);
}

// ---- build enT[l][c][k] = cb[l][k][c] * inv[l][k], 32-row LDS tiles ----
__global__ __launch_bounds__(256) void k_prep_enT(const float* __restrict__ cb,
                                                  const float* __restrict__ inv,
                                                  float* __restrict__ enT) {
  __shared__ float t[32][257];
  int l = blockIdx.x >> 7;             // grid = 4*128 = 512
  int kt = (blockIdx.x & 127) << 5;
  int tid = threadIdx.x;
#pragma unroll
  for (int i = 0; i < 32; ++i) {
    float sc = inv[l * 4096 + kt + i];
    t[i][tid] = cb[((l * 4096 + kt + i) << 8) + tid] * sc;
  }
  __syncthreads();
  int g = tid >> 5, j = tid & 31;
#pragma unroll
  for (int cc = 0; cc < 32; ++cc) {
    int c = cc * 8 + g;
    enT[((l << 8) + c) * 4096 + kt + j] = t[j][c];
  }
}

// ---- sim GEMM + partial argmax: block = 16 vectors x 1024-code slice ----
// grid id = s*256 + mt  (s = K-slice 0..3, mt = M-tile 0..255)
__global__ __launch_bounds__(256) void k_sim(const float* __restrict__ enT,
                                             const float* __restrict__ r,
                                             float* __restrict__ pval,
                                             int* __restrict__ pidx, int l) {
  __shared__ float rl[16 * 256];
  __shared__ float sv[4][16];
  __shared__ int   si[4][16];
  int id = blockIdx.x;
  int s = id >> 8, mt = id & 255;
  int mbase = mt * 16;
  int tid = threadIdx.x;
#pragma unroll
  for (int i = 0; i < 16; ++i)
    rl[i * 256 + tid] = r[(mbase + i) * 256 + tid];
  __syncthreads();

  int kbase = s * 1024 + tid * 4;
  const float* ep = enT + l * (256 * 4096) + kbase;

  float acc[16][4];
#pragma unroll
  for (int m = 0; m < 16; ++m)
#pragma unroll
    for (int j = 0; j < 4; ++j) acc[m][j] = 0.f;

  for (int c0 = 0; c0 < 256; c0 += 4) {
    float4 e0 = *(const float4*)(ep + (c0 + 0) * 4096);
    float4 e1 = *(const float4*)(ep + (c0 + 1) * 4096);
    float4 e2 = *(const float4*)(ep + (c0 + 2) * 4096);
    float4 e3 = *(const float4*)(ep + (c0 + 3) * 4096);
#pragma unroll
    for (int m = 0; m < 16; ++m) {
      float4 rv = *(const float4*)(rl + m * 256 + c0);  // LDS broadcast
      acc[m][0] = fmaf(rv.x, e0.x, fmaf(rv.y, e1.x, fmaf(rv.z, e2.x, fmaf(rv.w, e3.x, acc[m][0]))));
      acc[m][1] = fmaf(rv.x, e0.y, fmaf(rv.y, e1.y, fmaf(rv.z, e2.y, fmaf(rv.w, e3.y, acc[m][1]))));
      acc[m][2] = fmaf(rv.x, e0.z, fmaf(rv.y, e1.z, fmaf(rv.z, e2.z, fmaf(rv.w, e3.z, acc[m][2]))));
      acc[m][3] = fmaf(rv.x, e0.w, fmaf(rv.y, e1.w, fmaf(rv.z, e2.w, fmaf(rv.w, e3.w, acc[m][3]))));
    }
  }

  int lane = tid & 63, w = tid >> 6;
#pragma unroll
  for (int m = 0; m < 16; ++m) {
    float v = acc[m][0]; int ii = kbase;       // lowest j wins ties (strict >)
#pragma unroll
    for (int j = 1; j < 4; ++j)
      if (acc[m][j] > v) { v = acc[m][j]; ii = kbase + j; }
#pragma unroll
    for (int off = 1; off < 64; off <<= 1) {
      float ov = __shfl_xor(v, off); int oi = __shfl_xor(ii, off);
      if (ov > v || (ov == v && oi < ii)) { v = ov; ii = oi; }
    }
    if (lane == 0) { sv[w][m] = v; si[w][m] = ii; }
  }
  __syncthreads();
  if (tid < 16) {
    float v = sv[0][tid]; int ii = si[0][tid];
#pragma unroll
    for (int ww = 1; ww < 4; ++ww) {
      float ov = sv[ww][tid]; int oi = si[ww][tid];
      if (ov > v || (ov == v && oi < ii)) { v = ov; ii = oi; }
    }
    pval[(mbase + tid) * 4 + s] = v;
    pidx[(mbase + tid) * 4 + s] = ii;
  }
}

// ---- combine K-slices, write index, update residual, per-vector sumsq ----
__global__ __launch_bounds__(256) void k_update(const float* __restrict__ cb,
                                                float* __restrict__ r,
                                                const float* __restrict__ pval,
                                                const int* __restrict__ pidx,
                                                float* __restrict__ ssq,
                                                float* __restrict__ out_idx, int l) {
  __shared__ float wsum[4];
  int n = blockIdx.x, tid = threadIdx.x;
  float v = pval[n * 4]; int ii = pidx[n * 4];
#pragma unroll
  for (int s2 = 1; s2 < 4; ++s2) {
    float ov = pval[n * 4 + s2]; int oi = pidx[n * 4 + s2];
    if (ov > v || (ov == v && oi < ii)) { v = ov; ii = oi; }
  }
  if (tid == 0) out_idx[l * 4096 + n] = (float)ii;
  float e = cb[((l * 4096 + ii) << 8) + tid];     // original (input) codebook
  float rv = r[(n << 8) + tid] - e;
  r[(n << 8) + tid] = rv;
  float sq = rv * rv;
  int lane = tid & 63, w = tid >> 6;
#pragma unroll
  for (int off = 32; off; off >>= 1) sq += __shfl_xor(sq, off);
  if (lane == 0) wsum[w] = sq;
  __syncthreads();
  if (tid == 0) ssq[l * 4096 + n] = (wsum[0] + wsum[1]) + (wsum[2] + wsum[3]);
}

// ---- qloss: deterministic fixed-order reduction, single block ----
__global__ __launch_bounds__(256) void k_qloss(const float* __restrict__ ssq,
                                               float* __restrict__ out) {
  __shared__ float wsum[4];
  int tid = threadIdx.x;
  float q = 0.f;
  for (int l = 0; l < 4; ++l) {
    float p = 0.f;
#pragma unroll
    for (int i = 0; i < 16; ++i) p += ssq[l * 4096 + i * 256 + tid];
    int lane = tid & 63, w = tid >> 6;
#pragma unroll
    for (int off = 32; off; off >>= 1) p += __shfl_xor(p, off);
    if (lane == 0) wsum[w] = p;
    __syncthreads();
    float tot = (wsum[0] + wsum[1]) + (wsum[2] + wsum[3]);
    q += BETA * (tot * (1.0f / (4096.0f * 256.0f)));
    __syncthreads();
  }
  if (tid == 0) out[1048576 + 16384] = q;
}

// ---- z_q_st = z - residual_final, transposed back to (B,C,H,W) ----
__global__ __launch_bounds__(256) void k_writeq(const float* __restrict__ z,
                                                const float* __restrict__ r,
                                                float* __restrict__ out) {
  __shared__ float t[32][33];
  int id = blockIdx.x;
  int b = id >> 8; int rem = id & 255; int ct = rem >> 5; int ht = rem & 31;
  int c0 = ct * 32, h0 = ht * 32;
  int col = threadIdx.x & 31, row0 = threadIdx.x >> 5;
#pragma unroll
  for (int p = 0; p < 4; ++p) {
    int row = row0 + p * 8;            // hw offset
    t[row][col] = r[(b * 1024 + h0 + row) * 256 + c0 + col];
  }
  __syncthreads();
#pragma unroll
  for (int p = 0; p < 4; ++p) {
    int row = row0 + p * 8;            // c offset
    int o = ((b * 256 + c0 + row) << 10) + h0 + col;
    out[o] = z[o] - t[col][row];
  }
}

extern "C" void kernel_launch(void* const* d_in, const int* in_sizes, int n_in,
                              void* d_out, int out_size, void* d_ws, size_t ws_size,
                              hipStream_t stream) {
  const float* z  = (const float*)d_in[0];
  const float* cb = (const float*)d_in[1];
  float* out = (float*)d_out;
  float* ws  = (float*)d_ws;

  float* enT  = ws + OFF_ENT;
  float* r    = ws + OFF_R;
  float* inv  = ws + OFF_INV;
  float* pval = ws + OFF_PV;
  int*   pidx = (int*)(ws + OFF_PI);
  float* ssq  = ws + OFF_SSQ;

  k_prep_r<<<1024, 256, 0, stream>>>(z, r);
  k_prep_inv<<<4096, 256, 0, stream>>>(cb, inv);
  k_prep_enT<<<512, 256, 0, stream>>>(cb, inv, enT);
  for (int l = 0; l < 4; ++l) {
    k_sim<<<1024, 256, 0, stream>>>(enT, r, pval, pidx, l);
    k_update<<<4096, 256, 0, stream>>>(cb, r, pval, pidx, ssq, out + 1048576, l);
  }
  k_qloss<<<1, 256, 0, stream>>>(ssq, out);
  k_writeq<<<1024, 256, 0, stream>>>(z, r, out);
}

// Round 2
// 385.723 us; speedup vs baseline: 2.3246x; 2.3246x over previous
//
#include <hip/hip_runtime.h>

// Residual VQ (L=4, K=4096, C=256, N=4096) — bf16-split MFMA path.
// sim = rn . en^T computed as 6-term bf16 split GEMM (K' = 6*256 = 1536):
//   A segs: [hi, hi, mid, hi, lo, mid]   B segs: [hi, mid, hi, lo, hi, mid]
//   => hi*hi + hi*mid + mid*hi + hi*lo + lo*hi + mid*mid  (error ~2^-24 rel)
// ws layout (float units):
#define OFF_AS  0            // N x 1536 bf16  = 3145728 floats
#define OFF_BS  3145728      // K x 1536 bf16  = 3145728 floats
#define OFF_R   6291456      // N x C fp32     = 1048576
#define OFF_INV 7340032      // L x K          = 16384
#define OFF_PV  7356416      // N x 32         = 131072
#define OFF_PI  7487488      // N x 32 (int)   = 131072
#define OFF_SSQ 7618560      // L x N          = 16384
// total 7634944 floats ~ 30.5 MB

#define BETA 0.25f
#define EPSN 1e-12f
#define KP 1536

typedef __attribute__((ext_vector_type(8))) short short8;
typedef __attribute__((ext_vector_type(4))) float f32x4;

__device__ __forceinline__ unsigned short f2bf(float x) {
  unsigned u = __float_as_uint(x);
  unsigned r = (u + 0x7fffu + ((u >> 16) & 1u)) >> 16;
  return (unsigned short)r;
}
__device__ __forceinline__ float bf2f(unsigned short b) {
  return __uint_as_float(((unsigned)b) << 16);
}

__device__ __forceinline__ void gload16(const void* g, void* s) {
  __builtin_amdgcn_global_load_lds(
      (const __attribute__((address_space(1))) unsigned int*)g,
      (__attribute__((address_space(3))) unsigned int*)s, 16, 0, 0);
}

// ---- transpose z (B,C,H,W) -> r (N=B*HW, C) via 32x32 LDS tiles ----
__global__ __launch_bounds__(256) void k_prep_r(const float* __restrict__ z,
                                                float* __restrict__ r) {
  __shared__ float t[32][33];
  int id = blockIdx.x;                 // 4*8*32 = 1024
  int b = id >> 8; int rem = id & 255; int ct = rem >> 5; int ht = rem & 31;
  int c0 = ct * 32, h0 = ht * 32;
  int col = threadIdx.x & 31, row0 = threadIdx.x >> 5;
#pragma unroll
  for (int p = 0; p < 4; ++p) {
    int row = row0 + p * 8;
    t[row][col] = z[((b * 256 + c0 + row) << 10) + h0 + col];
  }
  __syncthreads();
#pragma unroll
  for (int p = 0; p < 4; ++p) {
    int row = row0 + p * 8;
    r[(b * 1024 + h0 + row) * 256 + c0 + col] = t[col][row];
  }
}

// ---- per-row inverse norms of codebook ----
__global__ __launch_bounds__(256) void k_prep_inv(const float* __restrict__ cb,
                                                  float* __restrict__ inv) {
  int w = threadIdx.x >> 6, lane = threadIdx.x & 63;
  int row = blockIdx.x * 4 + w;
  float4 v = *(const float4*)(cb + row * 256 + lane * 4);
  float s = v.x * v.x + v.y * v.y + v.z * v.z + v.w * v.w;
#pragma unroll
  for (int off = 32; off; off >>= 1) s += __shfl_xor(s, off);
  if (lane == 0) inv[row] = 1.0f / fmaxf(sqrtf(s), EPSN);
}

// ---- split residual rows into 6-seg bf16 A matrix (N x 1536) ----
__global__ __launch_bounds__(256) void k_split_a(const float* __restrict__ r,
                                                 unsigned short* __restrict__ AS) {
  int n = blockIdx.x, c = threadIdx.x;
  float x = r[n * 256 + c];
  unsigned short h = f2bf(x); float fh = bf2f(h);
  unsigned short m = f2bf(x - fh); float fm = bf2f(m);
  unsigned short lo = f2bf(x - fh - fm);
  unsigned short* row = AS + n * KP;
  row[c] = h; row[256 + c] = h; row[512 + c] = m;
  row[768 + c] = h; row[1024 + c] = lo; row[1280 + c] = m;
}

// ---- split normalized codebook rows into 6-seg bf16 B matrix (K x 1536) ----
__global__ __launch_bounds__(256) void k_bsplit(const float* __restrict__ cb,
                                                const float* __restrict__ inv,
                                                unsigned short* __restrict__ BS, int l) {
  int k = blockIdx.x, c = threadIdx.x;
  float x = cb[((l * 4096 + k) << 8) + c] * inv[l * 4096 + k];
  unsigned short h = f2bf(x); float fh = bf2f(h);
  unsigned short m = f2bf(x - fh); float fm = bf2f(m);
  unsigned short lo = f2bf(x - fh - fm);
  unsigned short* row = BS + k * KP;
  row[c] = h; row[256 + c] = m; row[512 + c] = h;
  row[768 + c] = lo; row[1024 + c] = h; row[1280 + c] = m;
}

// ---- 128x128-tile bf16 MFMA GEMM (A . B^T layout) + fused per-row argmax ----
// grid 1024: bm = wg>>5, bn = wg&31 after XCD swizzle
__global__ __launch_bounds__(256) void k_gemm_argmax(
    const unsigned short* __restrict__ AS, const unsigned short* __restrict__ BS,
    float* __restrict__ pval, int* __restrict__ pidx) {
  __shared__ unsigned short lA[128 * 64];  // [row][64k], chunk-swizzled
  __shared__ unsigned short lB[128 * 64];
  __shared__ float sv[2][2][64];
  __shared__ int   si[2][2][64];

  int bid = blockIdx.x;
  int wg = (bid & 7) * 128 + (bid >> 3);   // XCD-aware swizzle (1024 % 8 == 0)
  int bm = wg >> 5, bn = wg & 31;
  int mbase = bm * 128, nbase = bn * 128;
  int tid = threadIdx.x;
  int wid = tid >> 6, ln = tid & 63;
  int wr = wid >> 1, wc = wid & 1;
  int grp = ln >> 4, li = ln & 15;

  f32x4 acc[4][4];
#pragma unroll
  for (int i = 0; i < 4; ++i)
#pragma unroll
    for (int j = 0; j < 4; ++j) acc[i][j] = (f32x4){0.f, 0.f, 0.f, 0.f};

  for (int ks = 0; ks < 24; ++ks) {
    __syncthreads();
    int k0 = ks * 64;
    // stage A, B: linear LDS dest (wave-uniform + lane*16), pre-swizzled global src
#pragma unroll
    for (int i = 0; i < 4; ++i) {
      int idx = i * 256 + tid;               // 16B-chunk index 0..1023
      int row = idx >> 3, cc = idx & 7;
      int src = cc ^ (row & 7);
      gload16(AS + (mbase + row) * KP + k0 + src * 8, ((char*)lA) + idx * 16);
    }
#pragma unroll
    for (int i = 0; i < 4; ++i) {
      int idx = i * 256 + tid;
      int row = idx >> 3, cc = idx & 7;
      int src = cc ^ (row & 7);
      gload16(BS + (nbase + row) * KP + k0 + src * 8, ((char*)lB) + idx * 16);
    }
    __syncthreads();
#pragma unroll
    for (int kk = 0; kk < 2; ++kk) {
      short8 b[4];
#pragma unroll
      for (int ni = 0; ni < 4; ++ni) {
        int row = wc * 64 + ni * 16 + li;
        int cc = kk * 4 + grp;
        b[ni] = *(const short8*)(((const char*)lB) + row * 128 + (cc ^ (row & 7)) * 16);
      }
#pragma unroll
      for (int mi = 0; mi < 4; ++mi) {
        int row = wr * 64 + mi * 16 + li;
        int cc = kk * 4 + grp;
        short8 a = *(const short8*)(((const char*)lA) + row * 128 + (cc ^ (row & 7)) * 16);
#pragma unroll
        for (int ni = 0; ni < 4; ++ni)
          acc[mi][ni] = __builtin_amdgcn_mfma_f32_16x16x32_bf16(a, b[ni], acc[mi][ni], 0, 0, 0);
      }
    }
  }

  // ---- fused argmax epilogue ----
  // C/D: row = (ln>>4)*4 + reg (within 16x16 frag), col = ln&15
#pragma unroll
  for (int mi = 0; mi < 4; ++mi) {
#pragma unroll
    for (int reg = 0; reg < 4; ++reg) {
      float v = acc[mi][0][reg];
      int ii = nbase + wc * 64 + li;
#pragma unroll
      for (int ni = 1; ni < 4; ++ni) {
        float nv = acc[mi][ni][reg];
        if (nv > v) { v = nv; ii = nbase + wc * 64 + ni * 16 + li; }
      }
#pragma unroll
      for (int off = 1; off < 16; off <<= 1) {
        float ov = __shfl_xor(v, off);
        int oi = __shfl_xor(ii, off);
        if (ov > v || (ov == v && oi < ii)) { v = ov; ii = oi; }
      }
      int rrow = mi * 16 + grp * 4 + reg;
      if (li == 0) { sv[wr][wc][rrow] = v; si[wr][wc][rrow] = ii; }
    }
  }
  __syncthreads();
  if (tid < 128) {
    int wr2 = tid >> 6, r64 = tid & 63;
    float v0 = sv[wr2][0][r64]; int i0 = si[wr2][0][r64];
    float v1 = sv[wr2][1][r64]; int i1 = si[wr2][1][r64];
    if (v1 > v0 || (v1 == v0 && i1 < i0)) { v0 = v1; i0 = i1; }
    int n = mbase + wr2 * 64 + r64;
    pval[n * 32 + bn] = v0;
    pidx[n * 32 + bn] = i0;
  }
}

// ---- combine 32 col-slices, write index, update residual, sumsq ----
__global__ __launch_bounds__(256) void k_update(const float* __restrict__ cb,
                                                float* __restrict__ r,
                                                const float* __restrict__ pval,
                                                const int* __restrict__ pidx,
                                                float* __restrict__ ssq,
                                                float* __restrict__ out_idx, int l) {
  __shared__ float wsum[4];
  __shared__ int sidx;
  int n = blockIdx.x, tid = threadIdx.x;
  if (tid == 0) {
    float v = pval[n * 32]; int ii = pidx[n * 32];
    for (int s = 1; s < 32; ++s) {       // slices are ascending col ranges
      float ov = pval[n * 32 + s]; int oi = pidx[n * 32 + s];
      if (ov > v || (ov == v && oi < ii)) { v = ov; ii = oi; }
    }
    sidx = ii;
    out_idx[l * 4096 + n] = (float)ii;
  }
  __syncthreads();
  int ii = sidx;
  float e = cb[((l * 4096 + ii) << 8) + tid];
  float rv = r[(n << 8) + tid] - e;
  r[(n << 8) + tid] = rv;
  float sq = rv * rv;
  int lane = tid & 63, w = tid >> 6;
#pragma unroll
  for (int off = 32; off; off >>= 1) sq += __shfl_xor(sq, off);
  if (lane == 0) wsum[w] = sq;
  __syncthreads();
  if (tid == 0) ssq[l * 4096 + n] = (wsum[0] + wsum[1]) + (wsum[2] + wsum[3]);
}

// ---- qloss: fixed-order reduction ----
__global__ __launch_bounds__(256) void k_qloss(const float* __restrict__ ssq,
                                               float* __restrict__ out) {
  __shared__ float wsum[4];
  int tid = threadIdx.x;
  float q = 0.f;
  for (int l = 0; l < 4; ++l) {
    float p = 0.f;
#pragma unroll
    for (int i = 0; i < 16; ++i) p += ssq[l * 4096 + i * 256 + tid];
    int lane = tid & 63, w = tid >> 6;
#pragma unroll
    for (int off = 32; off; off >>= 1) p += __shfl_xor(p, off);
    if (lane == 0) wsum[w] = p;
    __syncthreads();
    float tot = (wsum[0] + wsum[1]) + (wsum[2] + wsum[3]);
    q += BETA * (tot * (1.0f / (4096.0f * 256.0f)));
    __syncthreads();
  }
  if (tid == 0) out[1048576 + 16384] = q;
}

// ---- z_q_st = z - residual_final, transposed back to (B,C,H,W) ----
__global__ __launch_bounds__(256) void k_writeq(const float* __restrict__ z,
                                                const float* __restrict__ r,
                                                float* __restrict__ out) {
  __shared__ float t[32][33];
  int id = blockIdx.x;
  int b = id >> 8; int rem = id & 255; int ct = rem >> 5; int ht = rem & 31;
  int c0 = ct * 32, h0 = ht * 32;
  int col = threadIdx.x & 31, row0 = threadIdx.x >> 5;
#pragma unroll
  for (int p = 0; p < 4; ++p) {
    int row = row0 + p * 8;
    t[row][col] = r[(b * 1024 + h0 + row) * 256 + c0 + col];
  }
  __syncthreads();
#pragma unroll
  for (int p = 0; p < 4; ++p) {
    int row = row0 + p * 8;
    int o = ((b * 256 + c0 + row) << 10) + h0 + col;
    out[o] = z[o] - t[col][row];
  }
}

extern "C" void kernel_launch(void* const* d_in, const int* in_sizes, int n_in,
                              void* d_out, int out_size, void* d_ws, size_t ws_size,
                              hipStream_t stream) {
  const float* z  = (const float*)d_in[0];
  const float* cb = (const float*)d_in[1];
  float* out = (float*)d_out;
  float* ws  = (float*)d_ws;

  unsigned short* AS = (unsigned short*)(ws + OFF_AS);
  unsigned short* BS = (unsigned short*)(ws + OFF_BS);
  float* r    = ws + OFF_R;
  float* inv  = ws + OFF_INV;
  float* pval = ws + OFF_PV;
  int*   pidx = (int*)(ws + OFF_PI);
  float* ssq  = ws + OFF_SSQ;

  k_prep_r<<<1024, 256, 0, stream>>>(z, r);
  k_prep_inv<<<4096, 256, 0, stream>>>(cb, inv);
  for (int l = 0; l < 4; ++l) {
    k_split_a<<<4096, 256, 0, stream>>>(r, AS);
    k_bsplit<<<4096, 256, 0, stream>>>(cb, inv, BS, l);
    k_gemm_argmax<<<1024, 256, 0, stream>>>(AS, BS, pval, pidx);
    k_update<<<4096, 256, 0, stream>>>(cb, r, pval, pidx, ssq, out + 1048576, l);
  }
  k_qloss<<<1, 256, 0, stream>>>(ssq, out);
  k_writeq<<<1024, 256, 0, stream>>>(z, r, out);
}